// Round 4
// baseline (109.160 us; speedup 1.0000x reference)
//
#include <hip/hip_runtime.h>
#include <hip/hip_bf16.h>

typedef __bf16 bf16_t;
typedef __bf16 bf16x8 __attribute__((ext_vector_type(8)));
typedef __bf16 bf16x4 __attribute__((ext_vector_type(4)));
typedef float  f32x4  __attribute__((ext_vector_type(4)));
typedef unsigned int u32;

#define DD    512
#define NTOK  2048
#define P_DEG 12   // |q*kappa| <= ~1.6 -> remainder ~7e-8

// async 16B global->LDS (dest is wave-uniform base + lane*16, linear)
__device__ __forceinline__ void gl_lds16(const bf16_t* g, bf16_t* l) {
    __builtin_amdgcn_global_load_lds((const u32*)g, (u32*)l, 16, 0, 0);
}

// DPP quad_perm all-reduce steps (xor1 = 0xB1, xor2 = 0x4E): VALU, no DS op
__device__ __forceinline__ float dpp_add_x1(float x) {
    int r = __builtin_amdgcn_mov_dpp(__float_as_int(x), 0xB1, 0xF, 0xF, true);
    return x + __int_as_float(r);
}
__device__ __forceinline__ float dpp_add_x2(float x) {
    int r = __builtin_amdgcn_mov_dpp(__float_as_int(x), 0x4E, 0xF, 0xF, true);
    return x + __int_as_float(r);
}

// ---- fp32 -> bf16 conversion of h + 4 weights (unchanged, R5-verified) ----
__global__ __launch_bounds__(256) void cvt_kernel(
    const float* __restrict__ h, const float* __restrict__ Wq,
    const float* __restrict__ Wk, const float* __restrict__ Wv,
    const float* __restrict__ Wo, bf16_t* __restrict__ hb, bf16_t* __restrict__ Wb)
{
    int idx = blockIdx.x * 256 + threadIdx.x;  // float4 index, 524288 total
    const float* src;
    bf16_t* dst;
    int off;
    if (idx < 262144) { src = h; dst = hb; off = idx; }
    else {
        int r = idx - 262144;
        int w = r >> 16;
        off = r & 65535;
        src = (w == 0) ? Wq : (w == 1) ? Wk : (w == 2) ? Wv : Wo;
        dst = Wb + (size_t)w * DD * DD;
    }
    f32x4 v = reinterpret_cast<const f32x4*>(src)[off];
    bf16x4 o;
    o[0] = (bf16_t)v[0]; o[1] = (bf16_t)v[1]; o[2] = (bf16_t)v[2]; o[3] = (bf16_t)v[3];
    reinterpret_cast<bf16x4*>(dst)[off] = o;
}

// QKV GEMM (unchanged, R5-verified): 64x64 tiles / BK=64 -> 768 blocks = 3/CU.
// Async global_load_lds double-buffer, one barrier per K-step, both-sides
// XOR involution swizzle (caveat-21).
__global__ __launch_bounds__(256) void qkv_kernel(
    const bf16_t* __restrict__ hb, const bf16_t* __restrict__ Wb,
    float* __restrict__ Q, float* __restrict__ Kp, float* __restrict__ V)
{
    __shared__ __align__(16) bf16_t sA[2][64 * 64];   // 8 KB per buf
    __shared__ __align__(16) bf16_t sB[2][64 * 64];   // 32 KB total

    const int tid  = threadIdx.x;
    const int lane = tid & 63;
    const int wvi  = tid >> 6;        // wave owns 16 token-rows
    const int fr   = lane & 15;
    const int q4   = lane >> 4;
    const int mBase = blockIdx.x * 64;
    const int nBase = blockIdx.y * 64;
    const int z    = blockIdx.z;
    const bf16_t* Am = hb + (size_t)mBase * DD;
    const bf16_t* Bm = Wb + (size_t)z * DD * DD + (size_t)nBase * DD;
    float* C = (z == 0) ? Q : (z == 1) ? Kp : V;
    const float scale = (z == 1) ? 0.04419417382415922f : 1.0f;  // 1/sqrt(512) into K'

    // tile = 512 16B-chunks; 2 issues x 256 lanes. chunk c: row=c>>3,
    // source col-chunk = (c&7) ^ (row&7), lands at linear LDS byte 16*c.
    const int c0 = tid;
    const int c1 = tid + 256;
    const int r0 = c0 >> 3, s0 = ((c0 & 7) ^ (r0 & 7)) * 8;
    const int r1 = c1 >> 3, s1 = ((c1 & 7) ^ (r1 & 7)) * 8;
    const int l0 = wvi * 512;          // wave-uniform LDS base (elems)
    const int l1 = l0 + 2048;

    const bf16_t* gA0 = Am + (size_t)r0 * DD + s0;
    const bf16_t* gA1 = Am + (size_t)r1 * DD + s1;
    const bf16_t* gB0 = Bm + (size_t)r0 * DD + s0;
    const bf16_t* gB1 = Bm + (size_t)r1 * DD + s1;

    f32x4 acc[4] = {};

#define STAGE_QKV(b, k0) do { \
        gl_lds16(gA0 + (k0), &sA[b][l0]); \
        gl_lds16(gA1 + (k0), &sA[b][l1]); \
        gl_lds16(gB0 + (k0), &sB[b][l0]); \
        gl_lds16(gB1 + (k0), &sB[b][l1]); } while (0)

    auto consume = [&](int b) {
        #pragma unroll
        for (int ks = 0; ks < 2; ++ks) {
            const int slot = ((ks * 4 + q4) ^ (fr & 7)) * 8;  // read-side XOR
            bf16x8 af = *reinterpret_cast<const bf16x8*>(&sA[b][(wvi * 16 + fr) * 64 + slot]);
            #pragma unroll
            for (int tj = 0; tj < 4; ++tj) {
                bf16x8 bw = *reinterpret_cast<const bf16x8*>(&sB[b][(tj * 16 + fr) * 64 + slot]);
                acc[tj] = __builtin_amdgcn_mfma_f32_16x16x32_bf16(af, bw, acc[tj], 0, 0, 0);
            }
        }
    };

    STAGE_QKV(0, 0);
    __syncthreads();                   // barrier drain waits vmcnt(0)
    int buf = 0;
    for (int t = 1; t < 8; ++t) {
        STAGE_QKV(buf ^ 1, t * 64);    // in flight during MFMA phase below
        consume(buf);
        __syncthreads();               // one barrier per K-step
        buf ^= 1;
    }
    consume(buf);
#undef STAGE_QKV

    // D[row=(lane>>4)*4+r][col=lane&15] (m89-verified)
    #pragma unroll
    for (int tj = 0; tj < 4; ++tj)
        #pragma unroll
        for (int r = 0; r < 4; ++r) {
            int gm = mBase + wvi * 16 + q4 * 4 + r;
            int gn = nBase + tj * 16 + fr;
            C[(size_t)gm * DD + gn] = acc[tj][r] * scale;
        }
}

// Fused moment-attention + out-projection. 128 blocks x 16 tokens, full
// N=512 per block. Phase 1: each wave computes moments for 4 tokens
// (unroll-2 interleave hides dependent-FMA latency at 1 wave/SIMD), O rows
// -> LDS bf16. Phase 2: out GEMM with A from LDS, B (Wo) streamed straight
// global->reg (waves own disjoint 128-col strips of Wo: zero cross-wave B
// reuse, so LDS-staging B would be pure overhead). Removes O round-trip +
// one launch boundary vs separate attn/out kernels.
__global__ __launch_bounds__(256) void attn_out_kernel(
    const float* __restrict__ Q, const float* __restrict__ Kp,
    const float* __restrict__ V, const bf16_t* __restrict__ Wob,
    float* __restrict__ out)
{
    __shared__ __align__(16) bf16_t sO[16][520];  // +8 pad: conflict-min A reads

    const int tid  = threadIdx.x;
    const int lane = tid & 63;
    const int wvi  = tid >> 6;

    const float INVF[P_DEG + 1] = {1.f, 1.f, 0.5f, 1.f/6.f, 1.f/24.f, 1.f/120.f,
        1.f/720.f, 1.f/5040.f, 1.f/40320.f, 1.f/362880.f, 1.f/3628800.f,
        1.f/39916800.f, 1.f/479001600.f};

    #pragma unroll 2
    for (int tt = 0; tt < 4; ++tt) {
        const int tl = wvi * 4 + tt;                 // local token row 0..15
        const int n  = blockIdx.x * 16 + tl;
        const float* kr = Kp + (size_t)n * DD + lane * 8;
        const float* vr = V  + (size_t)n * DD + lane * 8;
        const float* qr = Q  + (size_t)n * DD + lane * 8;

        f32x4 k0 = *reinterpret_cast<const f32x4*>(kr);
        f32x4 k1 = *reinterpret_cast<const f32x4*>(kr + 4);
        f32x4 v0 = *reinterpret_cast<const f32x4*>(vr);
        f32x4 v1 = *reinterpret_cast<const f32x4*>(vr + 4);
        f32x4 q0 = *reinterpret_cast<const f32x4*>(qr);      // issued early
        f32x4 q1 = *reinterpret_cast<const f32x4*>(qr + 4);
        float kap[8] = {k0[0], k0[1], k0[2], k0[3], k1[0], k1[1], k1[2], k1[3]};
        float vv[8]  = {v0[0], v0[1], v0[2], v0[3], v1[0], v1[1], v1[2], v1[3]};

        float md[P_DEG + 1] = {}, mc[P_DEG + 1] = {};
        #pragma unroll
        for (int j = 0; j < 8; j++) {
            float p = 1.f;
            mc[0] += vv[j];                       // md[0] is exact (=512)
            #pragma unroll
            for (int t = 1; t <= P_DEG; t++) {
                p *= kap[j];
                md[t] += p;
                mc[t] = fmaf(vv[j], p, mc[t]);
            }
        }
        #pragma unroll
        for (int t = 0; t <= P_DEG; t++) {
            mc[t] = dpp_add_x1(mc[t]);
            if (t) md[t] = dpp_add_x1(md[t]);
        }
        #pragma unroll
        for (int t = 0; t <= P_DEG; t++) {
            mc[t] = dpp_add_x2(mc[t]);
            if (t) md[t] = dpp_add_x2(md[t]);
        }
        #pragma unroll
        for (int m = 4; m <= 32; m <<= 1)
            #pragma unroll
            for (int t = 0; t <= P_DEG; t++) {
                mc[t] += __shfl_xor(mc[t], m);
                if (t) md[t] += __shfl_xor(md[t], m);
            }
        md[0] = 512.f;

        #pragma unroll
        for (int t = 1; t <= P_DEG; t++) { md[t] *= INVF[t]; mc[t] *= INVF[t]; }

        float qv[8] = {q0[0], q0[1], q0[2], q0[3], q1[0], q1[1], q1[2], q1[3]};

        bf16x8 ov;
        #pragma unroll
        for (int j = 0; j < 8; j++) {
            float x = qv[j];
            float F = mc[P_DEG], G = md[P_DEG];
            #pragma unroll
            for (int t = P_DEG - 1; t >= 0; t--) {
                F = fmaf(F, x, mc[t]);
                G = fmaf(G, x, md[t]);
            }
            ov[j] = (bf16_t)(F * __builtin_amdgcn_rcpf(G));
        }
        *reinterpret_cast<bf16x8*>(&sO[tl][lane * 8]) = ov;  // one 16B LDS store
    }
    __syncthreads();

    // ---- phase 2: out[16 tok][512] = O @ Wo^T, wave owns 128-col strip ----
    const int fr = lane & 15, q4 = lane >> 4;
    const int nBase = wvi * 128;
    const bf16_t* bp[8];
    #pragma unroll
    for (int nf = 0; nf < 8; ++nf)
        bp[nf] = Wob + (size_t)(nBase + nf * 16 + fr) * DD + q4 * 8;

    f32x4 acc[8] = {};
    #pragma unroll
    for (int k0 = 0; k0 < DD; k0 += 32) {
        bf16x8 af = *reinterpret_cast<const bf16x8*>(&sO[fr][k0 + q4 * 8]);
        #pragma unroll
        for (int nf = 0; nf < 8; ++nf) {
            bf16x8 bw = *reinterpret_cast<const bf16x8*>(bp[nf] + k0);
            acc[nf] = __builtin_amdgcn_mfma_f32_16x16x32_bf16(af, bw, acc[nf], 0, 0, 0);
        }
    }

    const int gmBase = blockIdx.x * 16 + q4 * 4;
    #pragma unroll
    for (int nf = 0; nf < 8; ++nf)
        #pragma unroll
        for (int r = 0; r < 4; ++r)
            out[(size_t)(gmBase + r) * DD + nBase + nf * 16 + fr] = acc[nf][r];
}

extern "C" void kernel_launch(void* const* d_in, const int* in_sizes, int n_in,
                              void* d_out, int out_size, void* d_ws, size_t ws_size,
                              hipStream_t stream)
{
    const float* h  = (const float*)d_in[0];
    const float* Wq = (const float*)d_in[1];
    const float* Wk = (const float*)d_in[2];
    const float* Wv = (const float*)d_in[3];
    const float* Wo = (const float*)d_in[4];
    float* out = (float*)d_out;

    float*  Q  = (float*)d_ws;                        // 4 MB
    float*  Kp = Q  + (size_t)NTOK * DD;              // 4 MB
    float*  V  = Kp + (size_t)NTOK * DD;              // 4 MB
    bf16_t* hb = (bf16_t*)(V + (size_t)NTOK * DD);    // 2 MB
    bf16_t* Wb = hb + (size_t)NTOK * DD;              // 2 MB

    cvt_kernel<<<dim3(2048), dim3(256), 0, stream>>>(h, Wq, Wk, Wv, Wo, hb, Wb);
    qkv_kernel<<<dim3(NTOK / 64, DD / 64, 3), dim3(256), 0, stream>>>(hb, Wb, Q, Kp, V);
    attn_out_kernel<<<dim3(NTOK / 16), dim3(256), 0, stream>>>(
        Q, Kp, V, Wb + (size_t)3 * DD * DD, out);
}

// Round 5
// 91.234 us; speedup vs baseline: 1.1965x; 1.1965x over previous
//
#include <hip/hip_runtime.h>
#include <hip/hip_bf16.h>

typedef __bf16 bf16_t;
typedef __bf16 bf16x8 __attribute__((ext_vector_type(8)));
typedef __bf16 bf16x4 __attribute__((ext_vector_type(4)));
typedef float  f32x4  __attribute__((ext_vector_type(4)));
typedef unsigned int u32;

#define DD    512
#define NTOK  2048
#define P_DEG 12   // |q*kappa| <= ~1.6 -> remainder ~7e-8

// async 16B global->LDS (dest is wave-uniform base + lane*16, linear)
__device__ __forceinline__ void gl_lds16(const bf16_t* g, bf16_t* l) {
    __builtin_amdgcn_global_load_lds((const u32*)g, (u32*)l, 16, 0, 0);
}

// DPP quad_perm all-reduce steps (xor1 = 0xB1, xor2 = 0x4E): VALU, no DS op
__device__ __forceinline__ float dpp_add_x1(float x) {
    int r = __builtin_amdgcn_mov_dpp(__float_as_int(x), 0xB1, 0xF, 0xF, true);
    return x + __int_as_float(r);
}
__device__ __forceinline__ float dpp_add_x2(float x) {
    int r = __builtin_amdgcn_mov_dpp(__float_as_int(x), 0x4E, 0xF, 0xF, true);
    return x + __int_as_float(r);
}

// ---- fp32 -> bf16 conversion of h + 4 weights ----
__global__ __launch_bounds__(256) void cvt_kernel(
    const float* __restrict__ h, const float* __restrict__ Wq,
    const float* __restrict__ Wk, const float* __restrict__ Wv,
    const float* __restrict__ Wo, bf16_t* __restrict__ hb, bf16_t* __restrict__ Wb)
{
    int idx = blockIdx.x * 256 + threadIdx.x;  // float4 index, 524288 total
    const float* src;
    bf16_t* dst;
    int off;
    if (idx < 262144) { src = h; dst = hb; off = idx; }
    else {
        int r = idx - 262144;
        int w = r >> 16;
        off = r & 65535;
        src = (w == 0) ? Wq : (w == 1) ? Wk : (w == 2) ? Wv : Wo;
        dst = Wb + (size_t)w * DD * DD;
    }
    f32x4 v = reinterpret_cast<const f32x4*>(src)[off];
    bf16x4 o;
    o[0] = (bf16_t)v[0]; o[1] = (bf16_t)v[1]; o[2] = (bf16_t)v[2]; o[3] = (bf16_t)v[3];
    reinterpret_cast<bf16x4*>(dst)[off] = o;
}

// QKV GEMM (R3-verified): 64x64 tiles / BK=64 -> 768 blocks = 3/CU.
// Async global_load_lds double-buffer, one barrier per K-step, both-sides
// XOR involution swizzle (caveat-21).
__global__ __launch_bounds__(256) void qkv_kernel(
    const bf16_t* __restrict__ hb, const bf16_t* __restrict__ Wb,
    float* __restrict__ Q, float* __restrict__ Kp, float* __restrict__ V)
{
    __shared__ __align__(16) bf16_t sA[2][64 * 64];   // 8 KB per buf
    __shared__ __align__(16) bf16_t sB[2][64 * 64];   // 32 KB total

    const int tid  = threadIdx.x;
    const int lane = tid & 63;
    const int wvi  = tid >> 6;        // wave owns 16 token-rows
    const int fr   = lane & 15;
    const int q4   = lane >> 4;
    const int mBase = blockIdx.x * 64;
    const int nBase = blockIdx.y * 64;
    const int z    = blockIdx.z;
    const bf16_t* Am = hb + (size_t)mBase * DD;
    const bf16_t* Bm = Wb + (size_t)z * DD * DD + (size_t)nBase * DD;
    float* C = (z == 0) ? Q : (z == 1) ? Kp : V;
    const float scale = (z == 1) ? 0.04419417382415922f : 1.0f;  // 1/sqrt(512) into K'

    // tile = 512 16B-chunks; 2 issues x 256 lanes. chunk c: row=c>>3,
    // source col-chunk = (c&7) ^ (row&7), lands at linear LDS byte 16*c.
    const int c0 = tid;
    const int c1 = tid + 256;
    const int r0 = c0 >> 3, s0 = ((c0 & 7) ^ (r0 & 7)) * 8;
    const int r1 = c1 >> 3, s1 = ((c1 & 7) ^ (r1 & 7)) * 8;
    const int l0 = wvi * 512;          // wave-uniform LDS base (elems)
    const int l1 = l0 + 2048;

    const bf16_t* gA0 = Am + (size_t)r0 * DD + s0;
    const bf16_t* gA1 = Am + (size_t)r1 * DD + s1;
    const bf16_t* gB0 = Bm + (size_t)r0 * DD + s0;
    const bf16_t* gB1 = Bm + (size_t)r1 * DD + s1;

    f32x4 acc[4] = {};

#define STAGE_QKV(b, k0) do { \
        gl_lds16(gA0 + (k0), &sA[b][l0]); \
        gl_lds16(gA1 + (k0), &sA[b][l1]); \
        gl_lds16(gB0 + (k0), &sB[b][l0]); \
        gl_lds16(gB1 + (k0), &sB[b][l1]); } while (0)

    auto consume = [&](int b) {
        #pragma unroll
        for (int ks = 0; ks < 2; ++ks) {
            const int slot = ((ks * 4 + q4) ^ (fr & 7)) * 8;  // read-side XOR
            bf16x8 af = *reinterpret_cast<const bf16x8*>(&sA[b][(wvi * 16 + fr) * 64 + slot]);
            #pragma unroll
            for (int tj = 0; tj < 4; ++tj) {
                bf16x8 bw = *reinterpret_cast<const bf16x8*>(&sB[b][(tj * 16 + fr) * 64 + slot]);
                acc[tj] = __builtin_amdgcn_mfma_f32_16x16x32_bf16(af, bw, acc[tj], 0, 0, 0);
            }
        }
    };

    STAGE_QKV(0, 0);
    __syncthreads();                   // barrier drain waits vmcnt(0)
    int buf = 0;
    for (int t = 1; t < 8; ++t) {
        STAGE_QKV(buf ^ 1, t * 64);    // in flight during MFMA phase below
        consume(buf);
        __syncthreads();               // one barrier per K-step
        buf ^= 1;
    }
    consume(buf);
#undef STAGE_QKV

    // D[row=(lane>>4)*4+r][col=lane&15] (m89-verified)
    #pragma unroll
    for (int tj = 0; tj < 4; ++tj)
        #pragma unroll
        for (int r = 0; r < 4; ++r) {
            int gm = mBase + wvi * 16 + q4 * 4 + r;
            int gn = nBase + tj * 16 + fr;
            C[(size_t)gm * DD + gn] = acc[tj][r] * scale;
        }
}

// out GEMM (R3-verified): 32x64 tiles -> 512 blocks = 2/CU, same 2-phase
// async structure as qkv.
__global__ __launch_bounds__(256) void out_kernel(
    const bf16_t* __restrict__ O, const bf16_t* __restrict__ Wob, float* __restrict__ out)
{
    __shared__ __align__(16) bf16_t sA[2][32 * 64];   // 4 KB per buf
    __shared__ __align__(16) bf16_t sB[2][64 * 64];   // 24 KB total

    const int tid  = threadIdx.x;
    const int lane = tid & 63;
    const int wvi  = tid >> 6;
    const int fr   = lane & 15;
    const int q4   = lane >> 4;
    const int mBase = blockIdx.x * 32, nBase = blockIdx.y * 64;

    const int c0 = tid;                // A chunk (256 total) + B chunk 0
    const int c1 = tid + 256;          // B chunk 1
    const int r0 = c0 >> 3, s0 = ((c0 & 7) ^ (r0 & 7)) * 8;
    const int r1 = c1 >> 3, s1 = ((c1 & 7) ^ (r1 & 7)) * 8;
    const int l0 = wvi * 512, l1 = l0 + 2048;

    const bf16_t* gA  = O   + (size_t)(mBase + r0) * DD + s0;
    const bf16_t* gB0 = Wob + (size_t)(nBase + r0) * DD + s0;
    const bf16_t* gB1 = Wob + (size_t)(nBase + r1) * DD + s1;

    f32x4 acc[2] = {};
    const int bbase = (wvi >> 1) * 32;  // wave owns 16 rows x 32 cols

#define STAGE_OUT(b, k0) do { \
        gl_lds16(gA  + (k0), &sA[b][l0]); \
        gl_lds16(gB0 + (k0), &sB[b][l0]); \
        gl_lds16(gB1 + (k0), &sB[b][l1]); } while (0)

    auto consume = [&](int b) {
        #pragma unroll
        for (int ks = 0; ks < 2; ++ks) {
            const int slot = ((ks * 4 + q4) ^ (fr & 7)) * 8;
            bf16x8 af = *reinterpret_cast<const bf16x8*>(&sA[b][((wvi & 1) * 16 + fr) * 64 + slot]);
            #pragma unroll
            for (int tj = 0; tj < 2; ++tj) {
                bf16x8 bw = *reinterpret_cast<const bf16x8*>(&sB[b][(bbase + tj * 16 + fr) * 64 + slot]);
                acc[tj] = __builtin_amdgcn_mfma_f32_16x16x32_bf16(af, bw, acc[tj], 0, 0, 0);
            }
        }
    };

    STAGE_OUT(0, 0);
    __syncthreads();
    int buf = 0;
    for (int t = 1; t < 8; ++t) {
        STAGE_OUT(buf ^ 1, t * 64);
        consume(buf);
        __syncthreads();
        buf ^= 1;
    }
    consume(buf);
#undef STAGE_OUT

    #pragma unroll
    for (int tj = 0; tj < 2; ++tj)
        #pragma unroll
        for (int r = 0; r < 4; ++r) {
            int gm = mBase + (wvi & 1) * 16 + q4 * 4 + r;
            int gn = nBase + bbase + tj * 16 + fr;
            out[(size_t)gm * DD + gn] = acc[tj][r];
        }
}

// Moment attention (R3-verified). Q loads hoisted, md[0]=512 analytic,
// xor1/xor2 butterfly steps via DPP quad_perm (VALU).
__global__ __launch_bounds__(256) void attn_kernel(
    const float* __restrict__ Q, const float* __restrict__ Kp,
    const float* __restrict__ V, bf16_t* __restrict__ O)
{
    const int n    = blockIdx.x * 4 + (threadIdx.x >> 6);
    const int lane = threadIdx.x & 63;
    const float* kr = Kp + (size_t)n * DD + lane * 8;
    const float* vr = V  + (size_t)n * DD + lane * 8;
    const float* qr = Q  + (size_t)n * DD + lane * 8;

    f32x4 k0 = *reinterpret_cast<const f32x4*>(kr);
    f32x4 k1 = *reinterpret_cast<const f32x4*>(kr + 4);
    f32x4 v0 = *reinterpret_cast<const f32x4*>(vr);
    f32x4 v1 = *reinterpret_cast<const f32x4*>(vr + 4);
    f32x4 q0 = *reinterpret_cast<const f32x4*>(qr);      // issued early,
    f32x4 q1 = *reinterpret_cast<const f32x4*>(qr + 4);  // used last
    float kap[8] = {k0[0], k0[1], k0[2], k0[3], k1[0], k1[1], k1[2], k1[3]};
    float vv[8]  = {v0[0], v0[1], v0[2], v0[3], v1[0], v1[1], v1[2], v1[3]};

    float md[P_DEG + 1] = {}, mc[P_DEG + 1] = {};
    #pragma unroll
    for (int j = 0; j < 8; j++) {
        float p = 1.f;
        mc[0] += vv[j];                       // t=0: md[0] is exact (=512)
        #pragma unroll
        for (int t = 1; t <= P_DEG; t++) {
            p *= kap[j];
            md[t] += p;
            mc[t] = fmaf(vv[j], p, mc[t]);
        }
    }
    #pragma unroll
    for (int t = 0; t <= P_DEG; t++) {
        mc[t] = dpp_add_x1(mc[t]);
        if (t) md[t] = dpp_add_x1(md[t]);
    }
    #pragma unroll
    for (int t = 0; t <= P_DEG; t++) {
        mc[t] = dpp_add_x2(mc[t]);
        if (t) md[t] = dpp_add_x2(md[t]);
    }
    #pragma unroll
    for (int m = 4; m <= 32; m <<= 1)
        #pragma unroll
        for (int t = 0; t <= P_DEG; t++) {
            mc[t] += __shfl_xor(mc[t], m);
            if (t) md[t] += __shfl_xor(md[t], m);
        }
    md[0] = 512.f;

    const float INVF[P_DEG + 1] = {1.f, 1.f, 0.5f, 1.f/6.f, 1.f/24.f, 1.f/120.f,
        1.f/720.f, 1.f/5040.f, 1.f/40320.f, 1.f/362880.f, 1.f/3628800.f,
        1.f/39916800.f, 1.f/479001600.f};
    #pragma unroll
    for (int t = 1; t <= P_DEG; t++) { md[t] *= INVF[t]; mc[t] *= INVF[t]; }

    float qv[8] = {q0[0], q0[1], q0[2], q0[3], q1[0], q1[1], q1[2], q1[3]};

    bf16x8 ov;
    #pragma unroll
    for (int j = 0; j < 8; j++) {
        float x = qv[j];
        float F = mc[P_DEG], G = md[P_DEG];
        #pragma unroll
        for (int t = P_DEG - 1; t >= 0; t--) {
            F = fmaf(F, x, mc[t]);
            G = fmaf(G, x, md[t]);
        }
        ov[j] = (bf16_t)(F * __builtin_amdgcn_rcpf(G));
    }
    *reinterpret_cast<bf16x8*>(O + (size_t)n * DD + lane * 8) = ov;
}

extern "C" void kernel_launch(void* const* d_in, const int* in_sizes, int n_in,
                              void* d_out, int out_size, void* d_ws, size_t ws_size,
                              hipStream_t stream)
{
    const float* h  = (const float*)d_in[0];
    const float* Wq = (const float*)d_in[1];
    const float* Wk = (const float*)d_in[2];
    const float* Wv = (const float*)d_in[3];
    const float* Wo = (const float*)d_in[4];
    float* out = (float*)d_out;

    float*  Q  = (float*)d_ws;                        // 4 MB
    float*  Kp = Q  + (size_t)NTOK * DD;              // 4 MB
    float*  V  = Kp + (size_t)NTOK * DD;              // 4 MB
    bf16_t* O  = (bf16_t*)(V + (size_t)NTOK * DD);    // 2 MB
    bf16_t* hb = O  + (size_t)NTOK * DD;              // 2 MB
    bf16_t* Wb = hb + (size_t)NTOK * DD;              // 2 MB

    cvt_kernel<<<dim3(2048), dim3(256), 0, stream>>>(h, Wq, Wk, Wv, Wo, hb, Wb);
    qkv_kernel<<<dim3(NTOK / 64, DD / 64, 3), dim3(256), 0, stream>>>(hb, Wb, Q, Kp, V);
    attn_kernel<<<dim3(NTOK / 4), dim3(256), 0, stream>>>(Q, Kp, V, O);
    out_kernel<<<dim3(NTOK / 32, DD / 64), dim3(256), 0, stream>>>(
        O, Wb + (size_t)3 * DD * DD, out);
}